// Round 1
// baseline (2115.727 us; speedup 1.0000x reference)
//
#include <hip/hip_runtime.h>
#include <math.h>

static constexpr int kN = 8192;
static constexpr int kD = 384;

// ---------------------------------------------------------------------------
// GEMM: Y[kN][kD] = X[kN][kD] @ W[kD][kD]^T   (Y[i][j] = sum_k X[i][k]*W[j][k])
// BM=64, BN=64, KC=32, 256 threads, 4x4 micro-tile
// ---------------------------------------------------------------------------
__global__ __launch_bounds__(256) void gemm_xwT_kernel(
    const float* __restrict__ X, const float* __restrict__ W,
    float* __restrict__ Y)
{
  __shared__ float Xs[64][33];
  __shared__ float WsT[32][68];
  const int tid = threadIdx.x;
  const int tx = tid & 15;
  const int ty = tid >> 4;
  const int i0 = blockIdx.x * 64;
  const int j0 = blockIdx.y * 64;
  float acc[4][4] = {};

  for (int k0 = 0; k0 < kD; k0 += 32) {
#pragma unroll
    for (int s = 0; s < 2; ++s) {
      const int f = tid + 256 * s;
      const int row = f >> 3;
      const int c4 = (f & 7) * 4;
      const float4 v = *reinterpret_cast<const float4*>(
          &X[(size_t)(i0 + row) * kD + k0 + c4]);
      Xs[row][c4 + 0] = v.x; Xs[row][c4 + 1] = v.y;
      Xs[row][c4 + 2] = v.z; Xs[row][c4 + 3] = v.w;
    }
#pragma unroll
    for (int s = 0; s < 2; ++s) {
      const int f = tid + 256 * s;
      const int col = f >> 3;
      const int c4 = (f & 7) * 4;
      const float4 v = *reinterpret_cast<const float4*>(
          &W[(size_t)(j0 + col) * kD + k0 + c4]);
      WsT[c4 + 0][col] = v.x; WsT[c4 + 1][col] = v.y;
      WsT[c4 + 2][col] = v.z; WsT[c4 + 3][col] = v.w;
    }
    __syncthreads();
#pragma unroll
    for (int kk = 0; kk < 32; ++kk) {
      const float4 b = *reinterpret_cast<const float4*>(&WsT[kk][tx * 4]);
      const float a0 = Xs[ty * 4 + 0][kk];
      const float a1 = Xs[ty * 4 + 1][kk];
      const float a2 = Xs[ty * 4 + 2][kk];
      const float a3 = Xs[ty * 4 + 3][kk];
      acc[0][0] += a0 * b.x; acc[0][1] += a0 * b.y; acc[0][2] += a0 * b.z; acc[0][3] += a0 * b.w;
      acc[1][0] += a1 * b.x; acc[1][1] += a1 * b.y; acc[1][2] += a1 * b.z; acc[1][3] += a1 * b.w;
      acc[2][0] += a2 * b.x; acc[2][1] += a2 * b.y; acc[2][2] += a2 * b.z; acc[2][3] += a2 * b.w;
      acc[3][0] += a3 * b.x; acc[3][1] += a3 * b.y; acc[3][2] += a3 * b.z; acc[3][3] += a3 * b.w;
    }
    __syncthreads();
  }
#pragma unroll
  for (int r = 0; r < 4; ++r) {
    float4 v;
    v.x = acc[r][0]; v.y = acc[r][1]; v.z = acc[r][2]; v.w = acc[r][3];
    *reinterpret_cast<float4*>(
        &Y[(size_t)(i0 + ty * 4 + r) * kD + j0 + tx * 4]) = v;
  }
}

// ---------------------------------------------------------------------------
// Flash attention (fp32, row-softmax over keys), 2-way key split.
// BM=32 rows/block, BN=128 keys/tile, KC=32, 256 threads.
// Thread (tx,ty): S rows ty*2+{0,1}; S cols {tx*4+cc, 64+tx*4+cc};
//                 O cols u*64 + tx*4 + cc, u=0..5.
// Writes UNNORMALIZED partial O plus per-row (m, l) for the merge.
// ---------------------------------------------------------------------------
static constexpr int BM = 32;
static constexpr int BN = 128;
static constexpr int KC = 32;
static constexpr int SPLIT = 2;
static constexpr int KEYS = kN / SPLIT;  // 4096

__global__ __launch_bounds__(256) void flash_kernel(
    const float* __restrict__ Q, const float* __restrict__ K,
    const float* __restrict__ V, float* __restrict__ Opart,
    float* __restrict__ ml)
{
  __shared__ float Qs[BM][KC + 1];
  __shared__ float KsT[KC][BN + 4];
  __shared__ float Ps[BM][BN + 4];
  __shared__ float Vs[BN][68];

  const int tid = threadIdx.x;
  const int tx = tid & 15;
  const int ty = tid >> 4;
  const int r0 = ty * 2;
  const int i0 = blockIdx.x * BM;
  const int sp = blockIdx.y;
  const int kbase = sp * KEYS;

  float o[2][6][4] = {};
  float m_run[2] = {-INFINITY, -INFINITY};
  float l_run[2] = {0.f, 0.f};

  for (int kb = 0; kb < KEYS; kb += BN) {
    const int kg = kbase + kb;
    float s[2][8];
#pragma unroll
    for (int q = 0; q < 2; ++q)
#pragma unroll
      for (int c = 0; c < 8; ++c) s[q][c] = 0.f;

    // ---- S = Q K^T over the D dimension ----
    for (int k0 = 0; k0 < kD; k0 += KC) {
      {
        const int row = tid >> 3;
        const int c4 = (tid & 7) * 4;
        const float4 v = *reinterpret_cast<const float4*>(
            &Q[(size_t)(i0 + row) * kD + k0 + c4]);
        Qs[row][c4 + 0] = v.x; Qs[row][c4 + 1] = v.y;
        Qs[row][c4 + 2] = v.z; Qs[row][c4 + 3] = v.w;
      }
#pragma unroll
      for (int st = 0; st < 4; ++st) {
        const int f = tid + 256 * st;
        const int key = f >> 3;
        const int c4 = (f & 7) * 4;
        const float4 v = *reinterpret_cast<const float4*>(
            &K[(size_t)(kg + key) * kD + k0 + c4]);
        KsT[c4 + 0][key] = v.x; KsT[c4 + 1][key] = v.y;
        KsT[c4 + 2][key] = v.z; KsT[c4 + 3][key] = v.w;
      }
      __syncthreads();
#pragma unroll
      for (int kk = 0; kk < KC; ++kk) {
        const float a0 = Qs[r0 + 0][kk];
        const float a1 = Qs[r0 + 1][kk];
        const float4 b0 = *reinterpret_cast<const float4*>(&KsT[kk][tx * 4]);
        const float4 b1 = *reinterpret_cast<const float4*>(&KsT[kk][64 + tx * 4]);
        s[0][0] += a0 * b0.x; s[0][1] += a0 * b0.y; s[0][2] += a0 * b0.z; s[0][3] += a0 * b0.w;
        s[0][4] += a0 * b1.x; s[0][5] += a0 * b1.y; s[0][6] += a0 * b1.z; s[0][7] += a0 * b1.w;
        s[1][0] += a1 * b0.x; s[1][1] += a1 * b0.y; s[1][2] += a1 * b0.z; s[1][3] += a1 * b0.w;
        s[1][4] += a1 * b1.x; s[1][5] += a1 * b1.y; s[1][6] += a1 * b1.z; s[1][7] += a1 * b1.w;
      }
      __syncthreads();
    }

    // ---- online softmax update ----
#pragma unroll
    for (int q = 0; q < 2; ++q) {
      float mt = s[q][0];
#pragma unroll
      for (int c = 1; c < 8; ++c) mt = fmaxf(mt, s[q][c]);
#pragma unroll
      for (int off = 1; off < 16; off <<= 1) mt = fmaxf(mt, __shfl_xor(mt, off, 64));
      const float mnew = fmaxf(m_run[q], mt);
      const float sc = expf(m_run[q] - mnew);
      float lt = 0.f;
#pragma unroll
      for (int c = 0; c < 8; ++c) {
        const float p = expf(s[q][c] - mnew);
        s[q][c] = p;
        lt += p;
      }
#pragma unroll
      for (int off = 1; off < 16; off <<= 1) lt += __shfl_xor(lt, off, 64);
      l_run[q] = l_run[q] * sc + lt;
      m_run[q] = mnew;
#pragma unroll
      for (int u = 0; u < 6; ++u)
#pragma unroll
        for (int cc = 0; cc < 4; ++cc) o[q][u][cc] *= sc;
#pragma unroll
      for (int h = 0; h < 2; ++h)
#pragma unroll
        for (int cc = 0; cc < 4; ++cc)
          Ps[r0 + q][h * 64 + tx * 4 + cc] = s[q][h * 4 + cc];
    }
    __syncthreads();

    // ---- O += P V, streaming V in 6 column chunks of 64 ----
#pragma unroll
    for (int u = 0; u < 6; ++u) {
#pragma unroll
      for (int st = 0; st < 8; ++st) {
        const int f = tid + 256 * st;
        const int key = f >> 4;
        const int c4 = (f & 15) * 4;
        const float4 v = *reinterpret_cast<const float4*>(
            &V[(size_t)(kg + key) * kD + u * 64 + c4]);
        Vs[key][c4 + 0] = v.x; Vs[key][c4 + 1] = v.y;
        Vs[key][c4 + 2] = v.z; Vs[key][c4 + 3] = v.w;
      }
      __syncthreads();
#pragma unroll 8
      for (int j = 0; j < BN; ++j) {
        const float p0 = Ps[r0 + 0][j];
        const float p1 = Ps[r0 + 1][j];
        const float4 v = *reinterpret_cast<const float4*>(&Vs[j][tx * 4]);
        o[0][u][0] += p0 * v.x; o[0][u][1] += p0 * v.y;
        o[0][u][2] += p0 * v.z; o[0][u][3] += p0 * v.w;
        o[1][u][0] += p1 * v.x; o[1][u][1] += p1 * v.y;
        o[1][u][2] += p1 * v.z; o[1][u][3] += p1 * v.w;
      }
      __syncthreads();
    }
  }

  float* Op = Opart + (size_t)sp * kN * kD;
#pragma unroll
  for (int q = 0; q < 2; ++q) {
#pragma unroll
    for (int u = 0; u < 6; ++u) {
      float4 v;
      v.x = o[q][u][0]; v.y = o[q][u][1]; v.z = o[q][u][2]; v.w = o[q][u][3];
      *reinterpret_cast<float4*>(
          &Op[(size_t)(i0 + r0 + q) * kD + u * 64 + tx * 4]) = v;
    }
  }
  if (tx == 0) {
#pragma unroll
    for (int q = 0; q < 2; ++q) {
      const size_t idx = ((size_t)sp * kN + i0 + r0 + q) * 2;
      ml[idx] = m_run[q];
      ml[idx + 1] = l_run[q];
    }
  }
}

// ---------------------------------------------------------------------------
// Merge the 2 key-split partials: O = sum_i e^{m_i-m} O~_i / sum_i e^{m_i-m} l_i
// ---------------------------------------------------------------------------
__global__ __launch_bounds__(256) void merge_kernel(
    const float* __restrict__ Opart, const float* __restrict__ ml,
    float* __restrict__ O)
{
  const size_t idx = (size_t)blockIdx.x * 256 + threadIdx.x;
  const size_t i = idx / kD;
  const float m0 = ml[i * 2];
  const float l0 = ml[i * 2 + 1];
  const float m1 = ml[((size_t)kN + i) * 2];
  const float l1 = ml[((size_t)kN + i) * 2 + 1];
  const float m = fmaxf(m0, m1);
  const float e0 = expf(m0 - m);
  const float e1 = expf(m1 - m);
  const float inv = 1.0f / (e0 * l0 + e1 * l1);
  O[idx] = (e0 * Opart[idx] + e1 * Opart[(size_t)kN * kD + idx]) * inv;
}

// ---------------------------------------------------------------------------
// Layer-2 helpers (only the last row of layer 2 is needed)
// ---------------------------------------------------------------------------
__global__ __launch_bounds__(64) void qrow_kernel(
    const float* __restrict__ h1, const float* __restrict__ Wq,
    float* __restrict__ q2)
{
  const int j = blockIdx.x;
  const int lane = threadIdx.x;
  const float* hr = h1 + (size_t)(kN - 1) * kD;
  float acc = 0.f;
  for (int d = lane; d < kD; d += 64) acc += hr[d] * Wq[(size_t)j * kD + d];
#pragma unroll
  for (int off = 32; off > 0; off >>= 1) acc += __shfl_xor(acc, off, 64);
  if (lane == 0) q2[j] = acc;
}

__global__ __launch_bounds__(256) void logits_kernel(
    const float* __restrict__ Kt2, const float* __restrict__ q2,
    float* __restrict__ lg)
{
  const int wave = threadIdx.x >> 6;
  const int lane = threadIdx.x & 63;
  const int j = blockIdx.x * 4 + wave;
  float acc = 0.f;
#pragma unroll
  for (int t = 0; t < kD / 64; ++t) {
    const int d = lane + t * 64;
    acc += Kt2[(size_t)j * kD + d] * q2[d];
  }
#pragma unroll
  for (int off = 32; off > 0; off >>= 1) acc += __shfl_xor(acc, off, 64);
  if (lane == 0) lg[j] = acc;
}

__global__ __launch_bounds__(1024) void smax_kernel(
    const float* __restrict__ lg, float* __restrict__ wgt)
{
  __shared__ float red[16];
  const int t = threadIdx.x;
  const int wave = t >> 6;
  const int lane = t & 63;
  float v[8];
  float mx = -INFINITY;
#pragma unroll
  for (int s = 0; s < 8; ++s) {
    v[s] = lg[t + 1024 * s];
    mx = fmaxf(mx, v[s]);
  }
#pragma unroll
  for (int off = 32; off > 0; off >>= 1) mx = fmaxf(mx, __shfl_xor(mx, off, 64));
  if (lane == 0) red[wave] = mx;
  __syncthreads();
  if (t == 0) {
    float m = red[0];
    for (int i = 1; i < 16; ++i) m = fmaxf(m, red[i]);
    red[0] = m;
  }
  __syncthreads();
  const float m = red[0];
  __syncthreads();
  float sum = 0.f;
#pragma unroll
  for (int s = 0; s < 8; ++s) {
    v[s] = expf(v[s] - m);
    sum += v[s];
  }
#pragma unroll
  for (int off = 32; off > 0; off >>= 1) sum += __shfl_xor(sum, off, 64);
  if (lane == 0) red[wave] = sum;
  __syncthreads();
  if (t == 0) {
    float S = 0.f;
    for (int i = 0; i < 16; ++i) S += red[i];
    red[0] = S;
  }
  __syncthreads();
  const float invS = 1.0f / red[0];
#pragma unroll
  for (int s = 0; s < 8; ++s) wgt[t + 1024 * s] = v[s] * invS;
}

// partial weighted sums: part[b][d] = sum_{j in block b's 256 rows} w[j]*Vt2[j][d]
__global__ __launch_bounds__(384) void wsum_kernel(
    const float* __restrict__ wgt, const float* __restrict__ Vt2,
    float* __restrict__ part)
{
  __shared__ float wl[256];
  const int b = blockIdx.x;
  const int t = threadIdx.x;
  if (t < 256) wl[t] = wgt[b * 256 + t];
  __syncthreads();
  const float* Vp = Vt2 + (size_t)b * 256 * kD;
  float acc = 0.f;
  for (int j = 0; j < 256; ++j) acc += wl[j] * Vp[(size_t)j * kD + t];
  part[b * kD + t] = acc;
}

__global__ __launch_bounds__(384) void final_kernel(
    const float* __restrict__ part, const float* __restrict__ ffws,
    float* __restrict__ out)
{
  __shared__ float red[6];
  const int t = threadIdx.x;
  const int wave = t >> 6;
  const int lane = t & 63;
  float z = 0.f;
#pragma unroll
  for (int b = 0; b < 32; ++b) z += part[b * kD + t];
  float val = z * ffws[t];
#pragma unroll
  for (int off = 32; off > 0; off >>= 1) val += __shfl_xor(val, off, 64);
  if (lane == 0) red[wave] = val;
  __syncthreads();
  if (t == 0) {
    float s = red[0];
    for (int i = 1; i < 6; ++i) s += red[i];
    out[0] = 1.0f / (1.0f + expf(-s));
  }
}

// ---------------------------------------------------------------------------
extern "C" void kernel_launch(void* const* d_in, const int* in_sizes, int n_in,
                              void* d_out, int out_size, void* d_ws, size_t ws_size,
                              hipStream_t stream) {
  const float* x    = (const float*)d_in[0];
  const float* Wq   = (const float*)d_in[1];
  const float* Wk   = (const float*)d_in[2];
  const float* Wv   = (const float*)d_in[3];
  const float* ffws = (const float*)d_in[4];
  float* out = (float*)d_out;
  float* ws  = (float*)d_ws;

  const size_t ND = (size_t)kN * kD;
  float* Qt   = ws;             // layer1 Q^T  [N][D]   (later reused: Kt2)
  float* Kt   = ws + ND;        // layer1 K^T  [N][D]   (later reused: Vt2)
  float* Vt   = ws + 2 * ND;    // layer1 V^T  [N][D]
  float* h1   = ws + 3 * ND;    // layer1 output [N][D]
  float* Op   = ws + 4 * ND;    // flash split partials [2][N][D]
  float* ml   = ws + 6 * ND;    // [2][N][2] (m, l)
  float* q2   = ml + 4 * (size_t)kN;
  float* lg   = q2 + kD;        // logits [N]
  float* wgt  = lg + kN;        // softmax weights [N]
  float* part = wgt + kN;       // [32][D]

  const dim3 gg(kN / 64, kD / 64);
  // ---- layer 1 projections ----
  gemm_xwT_kernel<<<gg, 256, 0, stream>>>(x, Wq, Qt);
  gemm_xwT_kernel<<<gg, 256, 0, stream>>>(x, Wk, Kt);
  gemm_xwT_kernel<<<gg, 256, 0, stream>>>(x, Wv, Vt);
  // ---- layer 1 attention ----
  flash_kernel<<<dim3(kN / BM, SPLIT), 256, 0, stream>>>(Qt, Kt, Vt, Op, ml);
  merge_kernel<<<(kN * kD) / 256, 256, 0, stream>>>(Op, ml, h1);
  // ---- layer 2 (only last output row needed) ----
  gemm_xwT_kernel<<<gg, 256, 0, stream>>>(h1, Wk, Qt);   // Kt2 -> Qt buffer
  gemm_xwT_kernel<<<gg, 256, 0, stream>>>(h1, Wv, Kt);   // Vt2 -> Kt buffer
  qrow_kernel<<<kD, 64, 0, stream>>>(h1, Wq, q2);
  logits_kernel<<<kN / 4, 256, 0, stream>>>(Qt, q2, lg);
  smax_kernel<<<1, 1024, 0, stream>>>(lg, wgt);
  wsum_kernel<<<32, 384, 0, stream>>>(wgt, Kt, part);
  final_kernel<<<1, 384, 0, stream>>>(part, ffws, out);
}

// Round 2
// 962.113 us; speedup vs baseline: 2.1990x; 2.1990x over previous
//
#include <hip/hip_runtime.h>
#include <hip/hip_bf16.h>
#include <math.h>

static constexpr int kN = 8192;
static constexpr int kD = 384;
static constexpr int kND = kN * kD;

typedef __attribute__((ext_vector_type(8))) short short8;
typedef __attribute__((ext_vector_type(4))) float f32x4;

// ---- bf16 helpers (bit-exact RNE, no API surprises) ----
__device__ __forceinline__ ushort f2bf(float f) {
  union { float f; unsigned int i; } cv; cv.f = f;
  unsigned int lsb = (cv.i >> 16) & 1u;
  unsigned int r = cv.i + 0x7fffu + lsb;
  return (ushort)(r >> 16);
}
__device__ __forceinline__ float bf2f(ushort u) {
  union { unsigned int i; float f; } cv; cv.i = ((unsigned int)u) << 16;
  return cv.f;
}
__device__ __forceinline__ f32x4 mfma_bf16(short8 a, short8 b, f32x4 c) {
  return __builtin_amdgcn_mfma_f32_16x16x32_bf16(a, b, c, 0, 0, 0);
}
// 3-term compensated product: ah*bh + ah*bl + al*bh  (error ~2^-16)
__device__ __forceinline__ f32x4 mfma3(short8 ah, short8 al, short8 bh, short8 bl, f32x4 c) {
  c = mfma_bf16(ah, bh, c);
  c = mfma_bf16(ah, bl, c);
  c = mfma_bf16(al, bh, c);
  return c;
}

// ---------------------------------------------------------------------------
// GEMM: Y = X[kN][kD] @ W[kD][kD]^T.
// MODE 0: fp32 out Y.  MODE 1: bf16 hi/lo out (row-major [N][D]).
// MODE 2: bf16 hi/lo out TRANSPOSED ([D][N]) for V.
// ---------------------------------------------------------------------------
template <int MODE>
__global__ __launch_bounds__(256) void gemm_xwT(
    const float* __restrict__ X, const float* __restrict__ W,
    float* __restrict__ Y, ushort* __restrict__ Yh, ushort* __restrict__ Yl)
{
  __shared__ float Xs[64][33];
  __shared__ float WsT[32][68];
  const int tid = threadIdx.x;
  const int tx = tid & 15;
  const int ty = tid >> 4;
  const int i0 = blockIdx.x * 64;
  const int j0 = blockIdx.y * 64;
  float acc[4][4] = {};

  for (int k0 = 0; k0 < kD; k0 += 32) {
#pragma unroll
    for (int s = 0; s < 2; ++s) {
      const int f = tid + 256 * s;
      const int row = f >> 3;
      const int c4 = (f & 7) * 4;
      const float4 v = *reinterpret_cast<const float4*>(
          &X[(size_t)(i0 + row) * kD + k0 + c4]);
      Xs[row][c4 + 0] = v.x; Xs[row][c4 + 1] = v.y;
      Xs[row][c4 + 2] = v.z; Xs[row][c4 + 3] = v.w;
    }
#pragma unroll
    for (int s = 0; s < 2; ++s) {
      const int f = tid + 256 * s;
      const int col = f >> 3;
      const int c4 = (f & 7) * 4;
      const float4 v = *reinterpret_cast<const float4*>(
          &W[(size_t)(j0 + col) * kD + k0 + c4]);
      WsT[c4 + 0][col] = v.x; WsT[c4 + 1][col] = v.y;
      WsT[c4 + 2][col] = v.z; WsT[c4 + 3][col] = v.w;
    }
    __syncthreads();
#pragma unroll
    for (int kk = 0; kk < 32; ++kk) {
      const float4 b = *reinterpret_cast<const float4*>(&WsT[kk][tx * 4]);
      const float a0 = Xs[ty * 4 + 0][kk];
      const float a1 = Xs[ty * 4 + 1][kk];
      const float a2 = Xs[ty * 4 + 2][kk];
      const float a3 = Xs[ty * 4 + 3][kk];
      acc[0][0] += a0 * b.x; acc[0][1] += a0 * b.y; acc[0][2] += a0 * b.z; acc[0][3] += a0 * b.w;
      acc[1][0] += a1 * b.x; acc[1][1] += a1 * b.y; acc[1][2] += a1 * b.z; acc[1][3] += a1 * b.w;
      acc[2][0] += a2 * b.x; acc[2][1] += a2 * b.y; acc[2][2] += a2 * b.z; acc[2][3] += a2 * b.w;
      acc[3][0] += a3 * b.x; acc[3][1] += a3 * b.y; acc[3][2] += a3 * b.z; acc[3][3] += a3 * b.w;
    }
    __syncthreads();
  }
  if constexpr (MODE == 0) {
#pragma unroll
    for (int r = 0; r < 4; ++r) {
      float4 v;
      v.x = acc[r][0]; v.y = acc[r][1]; v.z = acc[r][2]; v.w = acc[r][3];
      *reinterpret_cast<float4*>(
          &Y[(size_t)(i0 + ty * 4 + r) * kD + j0 + tx * 4]) = v;
    }
  } else if constexpr (MODE == 1) {
#pragma unroll
    for (int r = 0; r < 4; ++r) {
      ushort4 h, l;
      ushort* hp = &h.x; ushort* lp = &l.x;
#pragma unroll
      for (int c = 0; c < 4; ++c) {
        const float f = acc[r][c];
        const ushort hh = f2bf(f);
        hp[c] = hh;
        lp[c] = f2bf(f - bf2f(hh));
      }
      const int oi = (i0 + ty * 4 + r) * kD + j0 + tx * 4;
      *reinterpret_cast<ushort4*>(&Yh[oi]) = h;
      *reinterpret_cast<ushort4*>(&Yl[oi]) = l;
    }
  } else {
    // transposed store: VT[j][i]
#pragma unroll
    for (int c = 0; c < 4; ++c) {
      ushort4 h, l;
      ushort* hp = &h.x; ushort* lp = &l.x;
#pragma unroll
      for (int r = 0; r < 4; ++r) {
        const float f = acc[r][c];
        const ushort hh = f2bf(f);
        hp[r] = hh;
        lp[r] = f2bf(f - bf2f(hh));
      }
      const int oi = (j0 + tx * 4 + c) * kN + i0 + ty * 4;
      *reinterpret_cast<ushort4*>(&Yh[oi]) = h;
      *reinterpret_cast<ushort4*>(&Yl[oi]) = l;
    }
  }
}

// ---------------------------------------------------------------------------
// MFMA flash attention, bf16x3 compensated, fp32 accumulate.
// BM=64 q-rows/block, 4 waves, BN=128 keys/tile, SPLIT=2 (256 blocks, 1/CU).
// S^T = mfma(K,Q): lane owns q-row (col=l&15), keys at row=4*(l>>4)+reg.
// Wave w: S keys [32w,32w+32) of tile; PV output d-tiles dt == w (mod 4).
// Q-hi staged once in LDS; Q-lo/K frags straight from global (L2-resident).
// V pre-transposed in global -> contiguous b128 B-frags from LDS chunks (dbuf).
// ---------------------------------------------------------------------------
static constexpr int SPLITf = 2;
static constexpr int KEYSf = kN / SPLITf;  // 4096 -> 32 tiles of 128

__global__ __launch_bounds__(256, 1) void flash_mfma(
    const ushort* __restrict__ Qh, const ushort* __restrict__ Ql,
    const ushort* __restrict__ Kh, const ushort* __restrict__ Kl,
    const ushort* __restrict__ VTh, const ushort* __restrict__ VTl,
    float* __restrict__ Opart, float* __restrict__ ml)
{
  __shared__ ushort Qs[64 * 392];            // Q-hi [64][384] pad->392 (49x16B rows)
  __shared__ ushort PsH[64 * 136];           // P hi [64 qrows][128 keys] pad->136
  __shared__ ushort PsL[64 * 136];
  __shared__ ushort VsH[2][64 * 136];        // V^T chunk [64 dcols][128 keys], dbuf
  __shared__ ushort VsL[2][64 * 136];
  __shared__ float mlb_m[256];               // [wave][qt][16 rows]
  __shared__ float mlb_l[256];

  const int tid = threadIdx.x;
  const int w = tid >> 6;
  const int lane = tid & 63;
  const int l15 = lane & 15;
  const int hi4 = lane >> 4;
  const int sp = blockIdx.x;
  const int qb = blockIdx.y;
  const int i0 = qb * 64;
  const int kg0 = sp * KEYSf;

  // stage Q-hi once
  {
    const int row = tid >> 2;
    const int seg = (tid & 3) * 96;
    const ushort* src = Qh + (i0 + row) * kD + seg;
    ushort* dst = Qs + row * 392 + seg;
#pragma unroll
    for (int u = 0; u < 12; ++u)
      *reinterpret_cast<uint4*>(dst + 8 * u) =
          *reinterpret_cast<const uint4*>(src + 8 * u);
  }

  const f32x4 zf = {0.f, 0.f, 0.f, 0.f};
  f32x4 o[4][6];
#pragma unroll
  for (int qt = 0; qt < 4; ++qt)
#pragma unroll
    for (int c = 0; c < 6; ++c) o[qt][c] = zf;
  float m_run[4], l_run[4];
#pragma unroll
  for (int qt = 0; qt < 4; ++qt) { m_run[qt] = -INFINITY; l_run[qt] = 0.f; }

  const int qlbase = (i0 + l15) * kD + 8 * hi4;
  __syncthreads();

  for (int kb = 0; kb < KEYSf / 128; ++kb) {
    const int kg = kg0 + kb * 128;

    // ---- S^T phase: sacc[qt][kt], keys 32w+16kt+4*hi4+r, qrow 16qt+l15 ----
    f32x4 sacc[4][2];
#pragma unroll
    for (int qt = 0; qt < 4; ++qt) { sacc[qt][0] = zf; sacc[qt][1] = zf; }
    {
      const int kbase = (kg + 32 * w + l15) * kD + 8 * hi4;
#pragma unroll 3
      for (int ks = 0; ks < 12; ++ks) {
        const int d = 32 * ks;
        const short8 k0h = *reinterpret_cast<const short8*>(Kh + kbase + d);
        const short8 k0l = *reinterpret_cast<const short8*>(Kl + kbase + d);
        const short8 k1h = *reinterpret_cast<const short8*>(Kh + kbase + 6144 + d);
        const short8 k1l = *reinterpret_cast<const short8*>(Kl + kbase + 6144 + d);
#pragma unroll
        for (int qt = 0; qt < 4; ++qt) {
          const short8 qfh = *reinterpret_cast<const short8*>(
              Qs + (16 * qt + l15) * 392 + d + 8 * hi4);
          const short8 qfl = *reinterpret_cast<const short8*>(
              Ql + qlbase + 6144 * qt + d);
          sacc[qt][0] = mfma3(k0h, k0l, qfh, qfl, sacc[qt][0]);
          sacc[qt][1] = mfma3(k1h, k1l, qfh, qfl, sacc[qt][1]);
        }
      }
    }

    // ---- online softmax (lane-local rows; cross-wave via mlb) ----
    float sc[4];
#pragma unroll
    for (int qt = 0; qt < 4; ++qt) {
      float mt = sacc[qt][0][0];
#pragma unroll
      for (int kt = 0; kt < 2; ++kt)
#pragma unroll
        for (int r = 0; r < 4; ++r) mt = fmaxf(mt, sacc[qt][kt][r]);
      mt = fmaxf(mt, __shfl_xor(mt, 16, 64));
      mt = fmaxf(mt, __shfl_xor(mt, 32, 64));
      if (lane < 16) mlb_m[(w * 4 + qt) * 16 + l15] = mt;
    }
    __syncthreads();  // B1
#pragma unroll
    for (int qt = 0; qt < 4; ++qt) {
      const float Mt =
          fmaxf(fmaxf(mlb_m[qt * 16 + l15], mlb_m[(4 + qt) * 16 + l15]),
                fmaxf(mlb_m[(8 + qt) * 16 + l15], mlb_m[(12 + qt) * 16 + l15]));
      const float mnew = fmaxf(m_run[qt], Mt);
      sc[qt] = __expf(m_run[qt] - mnew);
      m_run[qt] = mnew;
      float ls = 0.f;
#pragma unroll
      for (int kt = 0; kt < 2; ++kt)
#pragma unroll
        for (int r = 0; r < 4; ++r) {
          const float p = __expf(sacc[qt][kt][r] - mnew);
          sacc[qt][kt][r] = p;
          ls += p;
        }
      ls += __shfl_xor(ls, 16, 64);
      ls += __shfl_xor(ls, 32, 64);
      if (lane < 16) mlb_l[(w * 4 + qt) * 16 + l15] = ls;
      // P -> LDS as bf16 hi/lo (pairs of consecutive keys -> one b32)
#pragma unroll
      for (int kt = 0; kt < 2; ++kt)
#pragma unroll
        for (int r = 0; r < 4; r += 2) {
          const float p0 = sacc[qt][kt][r], p1 = sacc[qt][kt][r + 1];
          const ushort h0 = f2bf(p0), h1 = f2bf(p1);
          const ushort g0 = f2bf(p0 - bf2f(h0)), g1 = f2bf(p1 - bf2f(h1));
          const int pi = (16 * qt + l15) * 136 + 32 * w + 16 * kt + 4 * hi4 + r;
          *reinterpret_cast<unsigned int*>(&PsH[pi]) =
              (unsigned int)h0 | ((unsigned int)h1 << 16);
          *reinterpret_cast<unsigned int*>(&PsL[pi]) =
              (unsigned int)g0 | ((unsigned int)g1 << 16);
        }
      // rescale O accumulator (per C-layout row 4*hi4+r)
#pragma unroll
      for (int r = 0; r < 4; ++r) {
        const float scr = __shfl(sc[qt], 4 * hi4 + r, 64);
#pragma unroll
        for (int c = 0; c < 6; ++c) o[qt][c][r] *= scr;
      }
    }
    __syncthreads();  // B2: Ps + mlb_l ready
#pragma unroll
    for (int qt = 0; qt < 4; ++qt)
      l_run[qt] = l_run[qt] * sc[qt] + mlb_l[qt * 16 + l15] +
                  mlb_l[(4 + qt) * 16 + l15] + mlb_l[(8 + qt) * 16 + l15] +
                  mlb_l[(12 + qt) * 16 + l15];

    // ---- PV phase: chunks of 64 dcols (dbuf), wave w computes dt = 4c+w ----
    auto stageV = [&](int c, int buf) {
      const int v = tid >> 2;
      const int k4 = (tid & 3) * 32;
      const int gsrc = (64 * c + v) * kN + kg + k4;
      const int ldst = v * 136 + k4;
#pragma unroll
      for (int u = 0; u < 4; ++u) {
        *reinterpret_cast<uint4*>(&VsH[buf][ldst + 8 * u]) =
            *reinterpret_cast<const uint4*>(VTh + gsrc + 8 * u);
        *reinterpret_cast<uint4*>(&VsL[buf][ldst + 8 * u]) =
            *reinterpret_cast<const uint4*>(VTl + gsrc + 8 * u);
      }
    };
    stageV(0, 0);
    __syncthreads();
#pragma unroll
    for (int c = 0; c < 6; ++c) {
      if (c < 5) stageV(c + 1, (c + 1) & 1);
      const int buf = c & 1;
#pragma unroll
      for (int ksv = 0; ksv < 4; ++ksv) {
        const int vb = (16 * w + l15) * 136 + 32 * ksv + 8 * hi4;
        const short8 vfh = *reinterpret_cast<const short8*>(&VsH[buf][vb]);
        const short8 vfl = *reinterpret_cast<const short8*>(&VsL[buf][vb]);
#pragma unroll
        for (int qt = 0; qt < 4; ++qt) {
          const int pb = (16 * qt + l15) * 136 + 32 * ksv + 8 * hi4;
          const short8 pfh = *reinterpret_cast<const short8*>(&PsH[pb]);
          const short8 pfl = *reinterpret_cast<const short8*>(&PsL[pb]);
          o[qt][c] = mfma3(pfh, pfl, vfh, vfl, o[qt][c]);
        }
      }
      __syncthreads();
    }
  }

  // ---- write unnormalized partials + (m,l) ----
#pragma unroll
  for (int qt = 0; qt < 4; ++qt)
#pragma unroll
    for (int c = 0; c < 6; ++c)
#pragma unroll
      for (int r = 0; r < 4; ++r)
        Opart[(size_t)sp * kND + (i0 + 16 * qt + 4 * hi4 + r) * kD +
              16 * (4 * c + w) + l15] = o[qt][c][r];
  if (w == 0 && lane < 16) {
#pragma unroll
    for (int qt = 0; qt < 4; ++qt) {
      const int mi = (sp * kN + i0 + 16 * qt + l15) * 2;
      ml[mi] = m_run[qt];
      ml[mi + 1] = l_run[qt];
    }
  }
}

// ---------------------------------------------------------------------------
// Merge 2 key-split partials
// ---------------------------------------------------------------------------
__global__ __launch_bounds__(256) void merge_kernel(
    const float* __restrict__ Opart, const float* __restrict__ ml,
    float* __restrict__ O)
{
  const size_t idx = (size_t)blockIdx.x * 256 + threadIdx.x;
  const size_t i = idx / kD;
  const float m0 = ml[i * 2];
  const float l0 = ml[i * 2 + 1];
  const float m1 = ml[((size_t)kN + i) * 2];
  const float l1 = ml[((size_t)kN + i) * 2 + 1];
  const float m = fmaxf(m0, m1);
  const float e0 = expf(m0 - m);
  const float e1 = expf(m1 - m);
  const float inv = 1.0f / (e0 * l0 + e1 * l1);
  O[idx] = (e0 * Opart[idx] + e1 * Opart[(size_t)kND + idx]) * inv;
}

// ---------------------------------------------------------------------------
// Layer-2 helpers (only last row of layer 2 needed)
// ---------------------------------------------------------------------------
__global__ __launch_bounds__(64) void qrow_kernel(
    const float* __restrict__ h1, const float* __restrict__ Wq,
    float* __restrict__ q2)
{
  const int j = blockIdx.x;
  const int lane = threadIdx.x;
  const float* hr = h1 + (size_t)(kN - 1) * kD;
  float acc = 0.f;
  for (int d = lane; d < kD; d += 64) acc += hr[d] * Wq[(size_t)j * kD + d];
#pragma unroll
  for (int off = 32; off > 0; off >>= 1) acc += __shfl_xor(acc, off, 64);
  if (lane == 0) q2[j] = acc;
}

__global__ __launch_bounds__(256) void logits_kernel(
    const float* __restrict__ Kt2, const float* __restrict__ q2,
    float* __restrict__ lg)
{
  const int wave = threadIdx.x >> 6;
  const int lane = threadIdx.x & 63;
  const int j = blockIdx.x * 4 + wave;
  float acc = 0.f;
#pragma unroll
  for (int t = 0; t < kD / 64; ++t) {
    const int d = lane + t * 64;
    acc += Kt2[(size_t)j * kD + d] * q2[d];
  }
#pragma unroll
  for (int off = 32; off > 0; off >>= 1) acc += __shfl_xor(acc, off, 64);
  if (lane == 0) lg[j] = acc;
}

__global__ __launch_bounds__(1024) void smax_kernel(
    const float* __restrict__ lg, float* __restrict__ wgt)
{
  __shared__ float red[16];
  const int t = threadIdx.x;
  const int wave = t >> 6;
  const int lane = t & 63;
  float v[8];
  float mx = -INFINITY;
#pragma unroll
  for (int s = 0; s < 8; ++s) {
    v[s] = lg[t + 1024 * s];
    mx = fmaxf(mx, v[s]);
  }
#pragma unroll
  for (int off = 32; off > 0; off >>= 1) mx = fmaxf(mx, __shfl_xor(mx, off, 64));
  if (lane == 0) red[wave] = mx;
  __syncthreads();
  if (t == 0) {
    float m = red[0];
    for (int i = 1; i < 16; ++i) m = fmaxf(m, red[i]);
    red[0] = m;
  }
  __syncthreads();
  const float m = red[0];
  __syncthreads();
  float sum = 0.f;
#pragma unroll
  for (int s = 0; s < 8; ++s) {
    v[s] = expf(v[s] - m);
    sum += v[s];
  }
#pragma unroll
  for (int off = 32; off > 0; off >>= 1) sum += __shfl_xor(sum, off, 64);
  if (lane == 0) red[wave] = sum;
  __syncthreads();
  if (t == 0) {
    float S = 0.f;
    for (int i = 0; i < 16; ++i) S += red[i];
    red[0] = S;
  }
  __syncthreads();
  const float invS = 1.0f / red[0];
#pragma unroll
  for (int s = 0; s < 8; ++s) wgt[t + 1024 * s] = v[s] * invS;
}

__global__ __launch_bounds__(384) void wsum_kernel(
    const float* __restrict__ wgt, const float* __restrict__ Vt2,
    float* __restrict__ part)
{
  __shared__ float wl[256];
  const int b = blockIdx.x;
  const int t = threadIdx.x;
  if (t < 256) wl[t] = wgt[b * 256 + t];
  __syncthreads();
  const float* Vp = Vt2 + (size_t)b * 256 * kD;
  float acc = 0.f;
  for (int j = 0; j < 256; ++j) acc += wl[j] * Vp[(size_t)j * kD + t];
  part[b * kD + t] = acc;
}

__global__ __launch_bounds__(384) void final_kernel(
    const float* __restrict__ part, const float* __restrict__ ffws,
    float* __restrict__ out)
{
  __shared__ float red[6];
  const int t = threadIdx.x;
  const int wave = t >> 6;
  const int lane = t & 63;
  float z = 0.f;
#pragma unroll
  for (int b = 0; b < 32; ++b) z += part[b * kD + t];
  float val = z * ffws[t];
#pragma unroll
  for (int off = 32; off > 0; off >>= 1) val += __shfl_xor(val, off, 64);
  if (lane == 0) red[wave] = val;
  __syncthreads();
  if (t == 0) {
    float s = red[0];
    for (int i = 1; i < 6; ++i) s += red[i];
    out[0] = 1.0f / (1.0f + expf(-s));
  }
}

// ---------------------------------------------------------------------------
extern "C" void kernel_launch(void* const* d_in, const int* in_sizes, int n_in,
                              void* d_out, int out_size, void* d_ws, size_t ws_size,
                              hipStream_t stream) {
  const float* x    = (const float*)d_in[0];
  const float* Wq   = (const float*)d_in[1];
  const float* Wk   = (const float*)d_in[2];
  const float* Wv   = (const float*)d_in[3];
  const float* ffws = (const float*)d_in[4];
  float* out = (float*)d_out;
  char* wsb = (char*)d_ws;

  // phase-1 layout (bytes):
  // [0..37.75M): Qh,Ql,Kh,Kl,VTh,VTl (bf16, kND each)
  // [37.75M..62.9M): Opart f32 [2][kND];  [62.9M..): ml f32 [2][kN][2]
  ushort* Qh  = (ushort*)wsb;
  ushort* Ql  = Qh + kND;
  ushort* Kh  = Ql + kND;
  ushort* Kl  = Kh + kND;
  ushort* VTh = Kl + kND;
  ushort* VTl = VTh + kND;
  float* Opart = (float*)(wsb + 6 * (size_t)kND * 2);
  float* ml    = Opart + 2 * (size_t)kND;
  // phase-2 overlays (flash buffers dead):
  float* Kt2 = (float*)wsb;                         // over Qh/Ql
  float* Vt2 = (float*)(wsb + 2 * (size_t)kND * 2); // over Kh/Kl
  float* h1  = (float*)(wsb + 4 * (size_t)kND * 2); // over VTh/VTl
  float* q2  = (float*)(wsb + 6 * (size_t)kND * 2); // over Opart
  float* lg  = q2 + kD;
  float* wgt = lg + kN;
  float* part = wgt + kN;

  const dim3 gg(kN / 64, kD / 64);
  // layer-1 projections -> bf16 hi/lo operands
  gemm_xwT<1><<<gg, 256, 0, stream>>>(x, Wq, nullptr, Qh, Ql);
  gemm_xwT<1><<<gg, 256, 0, stream>>>(x, Wk, nullptr, Kh, Kl);
  gemm_xwT<2><<<gg, 256, 0, stream>>>(x, Wv, nullptr, VTh, VTl);
  // layer-1 attention (MFMA flash)
  flash_mfma<<<dim3(SPLITf, kN / 64), 256, 0, stream>>>(
      Qh, Ql, Kh, Kl, VTh, VTl, Opart, ml);
  merge_kernel<<<(kN * kD) / 256, 256, 0, stream>>>(Opart, ml, h1);
  // layer 2 (only last output row needed)
  gemm_xwT<0><<<gg, 256, 0, stream>>>(h1, Wk, Kt2, nullptr, nullptr);
  gemm_xwT<0><<<gg, 256, 0, stream>>>(h1, Wv, Vt2, nullptr, nullptr);
  qrow_kernel<<<kD, 64, 0, stream>>>(h1, Wq, q2);
  logits_kernel<<<kN / 4, 256, 0, stream>>>(Kt2, q2, lg);
  smax_kernel<<<1, 1024, 0, stream>>>(lg, wgt);
  wsum_kernel<<<32, 384, 0, stream>>>(wgt, Vt2, part);
  final_kernel<<<1, 384, 0, stream>>>(part, ffws, out);
}